// Round 11
// baseline (4094.918 us; speedup 1.0000x reference)
//
#include <hip/hip_runtime.h>
#include <math.h>

// GnrlPatSoftmaxRNN: chunked low-rank reformulation.
// pat_t = S_t[p]*pat_t0[p,:] + S_t[p]*sum_s v_s[p]*h_s[:], analytic norm.
// Proven constraints (do not violate):
//   - launch_bounds(256,3) for kStep ((256,6) caps VGPR@40 -> spill: R3).
//   - hc and hn must not stream together through L1 (64KB>32KB L1: R5).
//   - two-pass sweep2 IS the L1 blocking; keep it (R5/R6).
//   - kStep phase structure is a LOCAL OPTIMUM (~122us, 3.3TB/s): merge (R5),
//     tile-fuse (R7), granule-split (R10) ALL lost by breaking the two clean
//     streaming phases. Do not restructure kStep again.
//   - occupancy/grid/unroll: not levers (R4/R9). Bytes x pattern-rate is.
// R13 best = 2846us: two-pass kStep + widened outred + 8-row sweep1 unroll.
// R15 (this): attack the ~890us non-kStep serial chain:
//   1) outred(c-1) moves INTO kStep(c) as 16 extra blocks/b (rides in
//      kStep's shadow). part double-buffered by chunk parity (race-free:
//      outred reads parity c-1, kStep writes parity c). kInner = solve only.
//   2) kPatR0 no longer copies pat (134MB write): kStep(c=0) reads patin
//      directly via a separate patread pointer, writes ws pat.

#define T_TOT 256
#define NB    64
#define NP    1024
#define NH    512
#define TC    16
#define NCH   (T_TOT / TC)
#define DECAYF 0.999f

__device__ __forceinline__ float dot4(float4 a, float4 b) {
    return a.x * b.x + a.y * b.y + a.z * b.z + a.w * b.w;
}
__device__ __forceinline__ void fma4(float4& acc, float s, float4 v) {
    acc.x += s * v.x; acc.y += s * v.y; acc.z += s * v.z; acc.w += s * v.w;
}
__device__ __forceinline__ void add4(float4& acc, float4 v) {
    acc.x += v.x; acc.y += v.y; acc.z += v.z; acc.w += v.w;
}

// ---------------------------------------------------------------- kG: Gram per chunk
__global__ __launch_bounds__(256) void kG(const float* __restrict__ x, float* __restrict__ G_all) {
    int c = blockIdx.x, b = blockIdx.y, tid = threadIdx.x;
    __shared__ float4 hs[TC][NH / 4 + 1];
    for (int idx = tid; idx < TC * (NH / 4); idx += 256) {
        int s = idx / (NH / 4), g = idx % (NH / 4);
        hs[s][g] = ((const float4*)x)[(size_t)((c * TC + s) * NB + b) * (NH / 4) + g];
    }
    __syncthreads();
    int si = tid / TC, ii = tid % TC;
    float acc = 0.f;
    for (int g = 0; g < NH / 4; g++) acc += dot4(hs[si][g], hs[ii][g]);
    G_all[(size_t)((c * NB + b) * TC + si) * TC + ii] = acc;
}

// ---------------------------------------------------------------- kPatR0: nrm + R0 for chunk 0 (no copy)
__global__ __launch_bounds__(256) void kPatR0(const float* __restrict__ src,
                                              const float* __restrict__ x, float* __restrict__ R0,
                                              float* __restrict__ inr_g, int c) {
    int b = blockIdx.y, tid = threadIdx.x;
    int w = tid >> 6, lane = tid & 63;
    int p0 = blockIdx.x * 64 + w * 16;
    __shared__ float scratch[4][16][65];
    const float4* x4 = (const float4*)x;
    float4 hnA[16], hnB[16];
#pragma unroll
    for (int s = 0; s < TC; s++) {
        size_t rb = (size_t)((c * TC + s) * NB + b) * (NH / 4);
        hnA[s] = x4[rb + lane];
        hnB[s] = x4[rb + 64 + lane];
    }
    const float4* s4 = (const float4*)src;
    for (int r = 0; r < 16; r++) {
        int p = p0 + r;
        size_t rowb = (size_t)(b * NP + p) * (NH / 4);
        float4 pvA = s4[rowb + lane];
        float4 pvB = s4[rowb + 64 + lane];
        float nrm = dot4(pvA, pvA) + dot4(pvB, pvB);
#pragma unroll
        for (int o = 32; o > 0; o >>= 1) nrm += __shfl_xor(nrm, o, 64);
        float inr = 1.0f / (sqrtf(nrm) + 1e-10f);
        float r0p[TC];
#pragma unroll
        for (int i = 0; i < TC; i++) r0p[i] = dot4(pvA, hnA[i]) + dot4(pvB, hnB[i]);
#pragma unroll
        for (int i = 0; i < TC; i++) scratch[w][i][lane] = r0p[i];
        int v = lane & 15, cq = lane >> 4;
        float part = 0.f;
#pragma unroll
        for (int j = 0; j < 16; j++) part += scratch[w][v][cq * 16 + j];
        part += __shfl_xor(part, 16, 64);
        part += __shfl_xor(part, 32, 64);
        if (lane < 16) R0[(size_t)(b * TC + v) * NP + p] = part * inr;
        if (lane == 0) inr_g[b * NP + p] = inr;
    }
}

// ---------------------------------------------------------------- kInner: serial 16-step solve only
__global__ __launch_bounds__(256, 1) void kInner(const float* __restrict__ R0, const float* __restrict__ G_all,
                                                 const float* __restrict__ inr_g, float* __restrict__ q_g,
                                                 float* __restrict__ wc_g, float* __restrict__ S_g,
                                                 float* __restrict__ Beta_g, int c) {
    int b = blockIdx.x, tid = threadIdx.x;
    int wid = tid >> 6, lane = tid & 63;
    __shared__ float Gs[TC * TC];
    __shared__ float redm[TC][4], reds[TC][4];
    __shared__ float betas[TC * TC];
    if (tid < TC * TC) {
        Gs[tid] = G_all[(size_t)(c * NB + b) * TC * TC + tid];
        betas[tid] = 0.f;
    }
    __syncthreads();
    const float* R0b = R0 + (size_t)b * TC * NP;
    float r0p[4][TC];
#pragma unroll
    for (int k = 0; k < 4; k++)
#pragma unroll
        for (int i = 0; i < TC; i++) r0p[k][i] = R0b[(size_t)i * NP + tid + 256 * k];

    float S[4] = {1.f, 1.f, 1.f, 1.f};
    float v[4][TC], q[4][TC];
    float raw[4];
#pragma unroll
    for (int i = 0; i < TC; i++) {
        float mymax = -1e30f;
#pragma unroll
        for (int k = 0; k < 4; k++) {
            float acc = r0p[k][i];
#pragma unroll
            for (int s = 0; s < i; s++) acc += v[k][s] * Gs[s * TC + i];
            raw[k] = S[k] * acc;
            mymax = fmaxf(mymax, raw[k]);
        }
#pragma unroll
        for (int o = 32; o > 0; o >>= 1) mymax = fmaxf(mymax, __shfl_xor(mymax, o, 64));
        if (lane == 0) redm[i][wid] = mymax;
        __syncthreads();
        float m = fmaxf(fmaxf(redm[i][0], redm[i][1]), fmaxf(redm[i][2], redm[i][3]));
        float hh = Gs[i * TC + i];
        float e[4], esum = 0.f;
#pragma unroll
        for (int k = 0; k < 4; k++) {
            float lg = (raw[k] >= 0.9f * m) ? (raw[k] / m) * 10.0f : 0.0f;
            e[k] = __expf(lg - 10.0f);
            esum += e[k];
        }
#pragma unroll
        for (int o = 32; o > 0; o >>= 1) esum += __shfl_xor(esum, o, 64);
        if (lane == 0) reds[i][wid] = esum;
        __syncthreads();
        float dinv = 1.0f / (reds[i][0] + reds[i][1] + reds[i][2] + reds[i][3]);
#pragma unroll
        for (int k = 0; k < 4; k++) {
            float pr = e[k] * dinv;
            q[k][i] = pr * S[k];
            float nn = sqrtf(DECAYF * DECAYF + 2.0f * DECAYF * pr * raw[k] + pr * pr * hh) + 1e-10f;
            v[k][i] = pr / (DECAYF * S[k]);
            S[k] = S[k] * (DECAYF / nn);
        }
    }
#pragma unroll
    for (int k = 0; k < 4; k++) {
        int p = tid + 256 * k;
        float inr = inr_g[b * NP + p];
        float4* qdst = (float4*)(q_g + (size_t)(b * NP + p) * TC);
        float4* wdst = (float4*)(wc_g + (size_t)(b * NP + p) * TC);
#pragma unroll
        for (int j = 0; j < 4; j++) {
            float4 tq, tw;
            tq.x = q[k][4 * j + 0] * inr; tq.y = q[k][4 * j + 1] * inr;
            tq.z = q[k][4 * j + 2] * inr; tq.w = q[k][4 * j + 3] * inr;
            tw.x = S[k] * v[k][4 * j + 0]; tw.y = S[k] * v[k][4 * j + 1];
            tw.z = S[k] * v[k][4 * j + 2]; tw.w = S[k] * v[k][4 * j + 3];
            qdst[j] = tq; wdst[j] = tw;
        }
        S_g[b * NP + p] = S[k] * inr;
    }
#pragma unroll
    for (int i = 1; i < TC; i++) {
#pragma unroll
        for (int s = 0; s < i; s++) {
            float prt = q[0][i] * v[0][s] + q[1][i] * v[1][s] + q[2][i] * v[2][s] + q[3][i] * v[3][s];
#pragma unroll
            for (int o = 32; o > 0; o >>= 1) prt += __shfl_xor(prt, o, 64);
            if (lane == 0) atomicAdd(&betas[i * TC + s], prt);
        }
    }
    __syncthreads();
    if (tid < TC * TC) {
        int i = tid / TC, s = tid % TC;
        Beta_g[(size_t)(c & 1) * NB * TC * TC + (size_t)b * TC * TC + tid] = (s < i) ? betas[tid] : 0.f;
    }
}

// ---------------------------------------------------------------- kStep: R9 two-pass body + fused outred(c-1)
// grid (NBLK + 16, NB). bx < NBLK: kStep proper (reads patread, writes pat,
//   writes part_w = parity c). bx >= NBLK: outred for chunk c-1 (reads
//   part_r = parity c-1 + Beta(c-1), writes out) -- rides in kStep's shadow.
// DO NOT restructure the two-pass body (R5/R7/R10 all lost).
template <int NBLK>
__global__ __launch_bounds__(256, 3) void kStep(float* __restrict__ pat, const float* __restrict__ patread,
                                                const float* __restrict__ x,
                                                const float* __restrict__ q_g, const float* __restrict__ wc_g,
                                                const float* __restrict__ S_g, float* __restrict__ R0,
                                                float* __restrict__ inr_g,
                                                float* __restrict__ part_w, const float* __restrict__ part_r,
                                                const float* __restrict__ Beta_g, float* __restrict__ out,
                                                int c, int do_upd) {
    constexpr int ROWS = NP / NBLK;
    int b = blockIdx.y, tid = threadIdx.x;
    int w = tid >> 6, lane = tid & 63;
    __shared__ __align__(16) float wcs[ROWS][20]; // wc(16)+Sf
    __shared__ float scratch[4][16][65];          // 16.6 KB: r0 transpose-reduce
    __shared__ float4 redbuf[4][128];             // 8 KB: outred cross-wave

    if (blockIdx.x >= NBLK) {
        // ---- outred path: chunk c-1, i = bx - NBLK ----
        if (c == 0) return;
        int cc = c - 1;
        int i = blockIdx.x - NBLK;
        const float4* part4 = (const float4*)part_r;
        float4 sumA = make_float4(0.f, 0.f, 0.f, 0.f), sumB = make_float4(0.f, 0.f, 0.f, 0.f);
        constexpr int PER = NBLK / 4;
        for (int t = 0; t < PER; t++) {
            int blk = w * PER + t;
            size_t base = ((((size_t)blk * NB + b) * TC) + i) * (NH / 4);
            add4(sumA, part4[base + lane]);
            add4(sumB, part4[base + 64 + lane]);
        }
        redbuf[w][lane] = sumA;
        redbuf[w][64 + lane] = sumB;
        __syncthreads();
        if (w == 0) {
            float4 sA = redbuf[0][lane], sB = redbuf[0][64 + lane];
            add4(sA, redbuf[1][lane]); add4(sB, redbuf[1][64 + lane]);
            add4(sA, redbuf[2][lane]); add4(sB, redbuf[2][64 + lane]);
            add4(sA, redbuf[3][lane]); add4(sB, redbuf[3][64 + lane]);
            const float4* x4 = (const float4*)x;
            const float* Bb = Beta_g + (size_t)(cc & 1) * NB * TC * TC + (size_t)b * TC * TC + i * TC;
#pragma unroll
            for (int s = 0; s < TC - 1; s++) {
                if (s < i) {
                    float beta = Bb[s];
                    size_t rb = (size_t)((cc * TC + s) * NB + b) * (NH / 4);
                    fma4(sA, beta, x4[rb + lane]);
                    fma4(sB, beta, x4[rb + 64 + lane]);
                }
            }
            size_t ob = (size_t)((cc * TC + i) * NB + b) * (NH / 4);
            ((float4*)out)[ob + lane] = sA;
            ((float4*)out)[ob + 64 + lane] = sB;
        }
        return;
    }

    int pbase = blockIdx.x * ROWS;
    if (do_upd) {
        const float4* wcg4 = (const float4*)(wc_g + (size_t)(b * NP + pbase) * TC);
        for (int idx = tid; idx < ROWS * 4; idx += 256) {
            float4 vv = wcg4[idx];
            *(float4*)&wcs[idx >> 2][(idx & 3) * 4] = vv;
        }
        for (int idx = tid; idx < ROWS; idx += 256) wcs[idx][16] = S_g[b * NP + pbase + idx];
    }

    // ---- sweep 1: out partials (8-row unroll, grouped loads) ----
    const float4* p4c = (const float4*)patread;
    float4 accA[4], accB[4];
#pragma unroll
    for (int j = 0; j < 4; j++) { accA[j] = make_float4(0.f, 0.f, 0.f, 0.f); accB[j] = make_float4(0.f, 0.f, 0.f, 0.f); }
    for (int rq = 0; rq < ROWS; rq += 8) {
        float4 pvA[8], pvB[8], qv[8];
#pragma unroll
        for (int u = 0; u < 8; u++) {
            int p = pbase + rq + u;
            size_t rowb = (size_t)(b * NP + p) * (NH / 4);
            pvA[u] = p4c[rowb + lane];
            pvB[u] = p4c[rowb + 64 + lane];
            qv[u] = *(const float4*)(q_g + (size_t)(b * NP + p) * TC + w * 4);
        }
#pragma unroll
        for (int u = 0; u < 8; u++) {
            fma4(accA[0], qv[u].x, pvA[u]); fma4(accB[0], qv[u].x, pvB[u]);
            fma4(accA[1], qv[u].y, pvA[u]); fma4(accB[1], qv[u].y, pvB[u]);
            fma4(accA[2], qv[u].z, pvA[u]); fma4(accB[2], qv[u].z, pvB[u]);
            fma4(accA[3], qv[u].w, pvA[u]); fma4(accB[3], qv[u].w, pvB[u]);
        }
    }
    float4* part4w = (float4*)part_w;
#pragma unroll
    for (int j = 0; j < 4; j++) {
        size_t pb = ((((size_t)blockIdx.x * NB + b) * TC) + (w * 4 + j)) * (NH / 4);
        part4w[pb + lane] = accA[j];
        part4w[pb + 64 + lane] = accB[j];
    }

    __syncthreads();  // all reads of pat rows done; LDS staging visible
    if (!do_upd) return;

    // ---- pass A: update + write + nrm (hc L1-resident) ----
    const float4* x4 = (const float4*)x;
    float4 hA[16], hB[16];
#pragma unroll
    for (int s = 0; s < TC; s++) {
        size_t rb = (size_t)((c * TC + s) * NB + b) * (NH / 4);
        hA[s] = x4[rb + lane];
        hB[s] = x4[rb + 64 + lane];
    }
    float4* p4 = (float4*)pat;
    for (int r = 0; r < ROWS / 4; r++) {
        int rr = w * (ROWS / 4) + r;
        int p = pbase + rr;
        size_t rowb = (size_t)(b * NP + p) * (NH / 4);
        float4 pvA = p4c[rowb + lane];
        float4 pvB = p4c[rowb + 64 + lane];
        float4 w0 = *(float4*)&wcs[rr][0];
        float4 w1 = *(float4*)&wcs[rr][4];
        float4 w2 = *(float4*)&wcs[rr][8];
        float4 w3 = *(float4*)&wcs[rr][12];
        float Sf = wcs[rr][16];
        float wcv[16] = {w0.x, w0.y, w0.z, w0.w, w1.x, w1.y, w1.z, w1.w,
                         w2.x, w2.y, w2.z, w2.w, w3.x, w3.y, w3.z, w3.w};
        float4 pnA, pnB;
        pnA.x = Sf * pvA.x; pnA.y = Sf * pvA.y; pnA.z = Sf * pvA.z; pnA.w = Sf * pvA.w;
        pnB.x = Sf * pvB.x; pnB.y = Sf * pvB.y; pnB.z = Sf * pvB.z; pnB.w = Sf * pvB.w;
#pragma unroll
        for (int s = 0; s < TC; s++) {
            fma4(pnA, wcv[s], hA[s]);
            fma4(pnB, wcv[s], hB[s]);
        }
        p4[rowb + lane] = pnA;
        p4[rowb + 64 + lane] = pnB;
        float nrm = dot4(pnA, pnA) + dot4(pnB, pnB);
#pragma unroll
        for (int o = 32; o > 0; o >>= 1) nrm += __shfl_xor(nrm, o, 64);
        float inr = 1.0f / (sqrtf(nrm) + 1e-10f);
        if (lane == 0) inr_g[b * NP + p] = inr;
    }

    // ---- pass B: r0 vs next chunk (hn L1-resident; pn re-read L2-hot) ----
#pragma unroll
    for (int s = 0; s < TC; s++) {
        size_t rb = (size_t)(((c + 1) * TC + s) * NB + b) * (NH / 4);
        hA[s] = x4[rb + lane];
        hB[s] = x4[rb + 64 + lane];
    }
    for (int r = 0; r < ROWS / 4; r++) {
        int rr = w * (ROWS / 4) + r;
        int p = pbase + rr;
        size_t rowb = (size_t)(b * NP + p) * (NH / 4);
        float4 pnA = p4[rowb + lane];
        float4 pnB = p4[rowb + 64 + lane];
        float inr = inr_g[b * NP + p];
        float r0p[TC];
#pragma unroll
        for (int i = 0; i < TC; i++) r0p[i] = dot4(pnA, hA[i]) + dot4(pnB, hB[i]);
#pragma unroll
        for (int i = 0; i < TC; i++) scratch[w][i][lane] = r0p[i];
        int v = lane & 15, cq = lane >> 4;
        float ps = 0.f;
#pragma unroll
        for (int j = 0; j < 16; j++) ps += scratch[w][v][cq * 16 + j];
        ps += __shfl_xor(ps, 16, 64);
        ps += __shfl_xor(ps, 32, 64);
        if (lane < 16) R0[(size_t)(b * TC + v) * NP + p] = ps * inr;
    }
}

// ---------------------------------------------------------------- kOutRed: standalone for the last chunk
__global__ __launch_bounds__(256) void kOutRed(const float* __restrict__ part, const float* __restrict__ x,
                                               const float* __restrict__ Beta_g, float* __restrict__ out,
                                               int npb, int c) {
    int b = blockIdx.y, i = blockIdx.x, tid = threadIdx.x;
    int wid = tid >> 6, lane = tid & 63;
    __shared__ float4 redbuf[4][128];
    const float4* part4 = (const float4*)part;
    float4 sumA = make_float4(0.f, 0.f, 0.f, 0.f), sumB = make_float4(0.f, 0.f, 0.f, 0.f);
    int per = npb >> 2;
    for (int t = 0; t < per; t++) {
        int blk = wid * per + t;
        size_t base = ((((size_t)blk * NB + b) * TC) + i) * (NH / 4);
        add4(sumA, part4[base + lane]);
        add4(sumB, part4[base + 64 + lane]);
    }
    redbuf[wid][lane] = sumA;
    redbuf[wid][64 + lane] = sumB;
    __syncthreads();
    if (wid == 0) {
        float4 sA = redbuf[0][lane], sB = redbuf[0][64 + lane];
        add4(sA, redbuf[1][lane]); add4(sB, redbuf[1][64 + lane]);
        add4(sA, redbuf[2][lane]); add4(sB, redbuf[2][64 + lane]);
        add4(sA, redbuf[3][lane]); add4(sB, redbuf[3][64 + lane]);
        const float4* x4 = (const float4*)x;
        const float* Bb = Beta_g + (size_t)b * TC * TC + i * TC;
#pragma unroll
        for (int s = 0; s < TC - 1; s++) {
            if (s < i) {
                float beta = Bb[s];
                size_t rb = (size_t)((c * TC + s) * NB + b) * (NH / 4);
                fma4(sA, beta, x4[rb + lane]);
                fma4(sB, beta, x4[rb + 64 + lane]);
            }
        }
        size_t ob = (size_t)((c * TC + i) * NB + b) * (NH / 4);
        ((float4*)out)[ob + lane] = sA;
        ((float4*)out)[ob + 64 + lane] = sB;
    }
}

// ---------------------------------------------------------------- launch
extern "C" void kernel_launch(void* const* d_in, const int* in_sizes, int n_in,
                              void* d_out, int out_size, void* d_ws, size_t ws_size,
                              hipStream_t stream) {
    const float* x = (const float*)d_in[0];      // [T,B,H]
    const float* patin = (const float*)d_in[1];  // [B,P,H]
    float* out = (float*)d_out;                  // [T,B,H]

    char* ws = (char*)d_ws;
    size_t off = 0;
    auto alloc = [&](size_t nfloats) { float* r = (float*)(ws + off); off += nfloats * sizeof(float); return r; };

    // fixed small buffers (~13.8 MB)
    float* R0 = alloc((size_t)NB * TC * NP);
    float* q_g = alloc((size_t)NB * TC * NP);
    float* wc_g = alloc((size_t)NB * TC * NP);
    float* S_g = alloc((size_t)NB * NP);
    float* inr_g = alloc((size_t)NB * NP);
    float* G_all = alloc((size_t)NCH * NB * TC * TC);
    float* Beta = alloc((size_t)2 * NB * TC * TC);  // parity double-buffered

    // part: parity double-buffered (fused outred reads c-1 while kStep writes c)
    const size_t partUnit = (size_t)NB * TC * NH;   // floats per p-block
    const size_t patN = (size_t)NB * NP * NH;
    int nblk;
    if (ws_size >= off + (2 * 16 * partUnit + patN) * sizeof(float)) nblk = 16;
    else nblk = 8;
    const size_t partN = (size_t)nblk * partUnit;
    float* part0 = alloc(partN);
    float* part1 = alloc(partN);

    // pat: workspace if it fits, else in-place (harness restores input per launch)
    float* pat;
    if (ws_size >= off + patN * sizeof(float)) {
        pat = alloc(patN);
    } else {
        pat = (float*)d_in[1];
    }

    kG<<<dim3(NCH, NB), 256, 0, stream>>>(x, G_all);
    kPatR0<<<dim3(16, NB), 256, 0, stream>>>(patin, x, R0, inr_g, 0);
    for (int c = 0; c < NCH; c++) {
        kInner<<<NB, 256, 0, stream>>>(R0, G_all, inr_g, q_g, wc_g, S_g, Beta, c);
        int du = (c + 1 < NCH) ? 1 : 0;
        float* pw = (c & 1) ? part1 : part0;
        const float* pr = (c & 1) ? part0 : part1;   // parity c-1
        const float* patread = (c == 0) ? patin : pat;
        if (nblk == 16)
            kStep<16><<<dim3(32, NB), 256, 0, stream>>>(pat, patread, x, q_g, wc_g, S_g, R0, inr_g,
                                                        pw, pr, Beta, out, c, du);
        else
            kStep<8><<<dim3(24, NB), 256, 0, stream>>>(pat, patread, x, q_g, wc_g, S_g, R0, inr_g,
                                                       pw, pr, Beta, out, c, du);
    }
    const float* lastPart = ((NCH - 1) & 1) ? part1 : part0;
    kOutRed<<<dim3(16, NB), 256, 0, stream>>>(lastPart, x, Beta + (size_t)((NCH - 1) & 1) * NB * TC * TC,
                                              out, nblk, NCH - 1);
}

// Round 12
// 3584.718 us; speedup vs baseline: 1.1423x; 1.1423x over previous
//
#include <hip/hip_runtime.h>
#include <math.h>

// GnrlPatSoftmaxRNN: chunked low-rank reformulation.
// pat_t = S_t[p]*pat_t0[p,:] + S_t[p]*sum_s v_s[p]*h_s[:], analytic norm.
// Proven constraints (do not violate):
//   - launch_bounds(256,3) for kStep ((256,6) caps VGPR@40 -> spill: R3).
//   - hc and hn must not stream together through L1 (64KB>32KB L1: R5).
//   - two-pass sweep2 IS the L1 blocking; keep it (R5/R6).
//   - kStep phase structure is a LOCAL OPTIMUM: merge (R5), tile-fuse (R7),
//     granule-split (R10) all lost. Do not restructure.
//   - kStep rate is occupancy-sensitive: +8KB LDS (R11: 22016->30208) cut
//     occupancy 24.9->15.8% and rate 3.3->2.2 TB/s. Keep LDS at 22016.
// R15 (R11): outred(c-1) fused into kStep(c) as 16 extra blocks, part
//   parity-buffered; kPatR0 copy deleted (kStep c=0 reads patin directly).
//   Passed, but redbuf LDS cost the occupancy above.
// R16 (this): identical to R11 except redbuf ALIASES scratch (outred path
//   never uses scratch; kStep path never uses redbuf) -> LDS back to 22016.

#define T_TOT 256
#define NB    64
#define NP    1024
#define NH    512
#define TC    16
#define NCH   (T_TOT / TC)
#define DECAYF 0.999f

__device__ __forceinline__ float dot4(float4 a, float4 b) {
    return a.x * b.x + a.y * b.y + a.z * b.z + a.w * b.w;
}
__device__ __forceinline__ void fma4(float4& acc, float s, float4 v) {
    acc.x += s * v.x; acc.y += s * v.y; acc.z += s * v.z; acc.w += s * v.w;
}
__device__ __forceinline__ void add4(float4& acc, float4 v) {
    acc.x += v.x; acc.y += v.y; acc.z += v.z; acc.w += v.w;
}

// ---------------------------------------------------------------- kG: Gram per chunk
__global__ __launch_bounds__(256) void kG(const float* __restrict__ x, float* __restrict__ G_all) {
    int c = blockIdx.x, b = blockIdx.y, tid = threadIdx.x;
    __shared__ float4 hs[TC][NH / 4 + 1];
    for (int idx = tid; idx < TC * (NH / 4); idx += 256) {
        int s = idx / (NH / 4), g = idx % (NH / 4);
        hs[s][g] = ((const float4*)x)[(size_t)((c * TC + s) * NB + b) * (NH / 4) + g];
    }
    __syncthreads();
    int si = tid / TC, ii = tid % TC;
    float acc = 0.f;
    for (int g = 0; g < NH / 4; g++) acc += dot4(hs[si][g], hs[ii][g]);
    G_all[(size_t)((c * NB + b) * TC + si) * TC + ii] = acc;
}

// ---------------------------------------------------------------- kPatR0: nrm + R0 for chunk 0 (no copy)
__global__ __launch_bounds__(256) void kPatR0(const float* __restrict__ src,
                                              const float* __restrict__ x, float* __restrict__ R0,
                                              float* __restrict__ inr_g, int c) {
    int b = blockIdx.y, tid = threadIdx.x;
    int w = tid >> 6, lane = tid & 63;
    int p0 = blockIdx.x * 64 + w * 16;
    __shared__ float scratch[4][16][65];
    const float4* x4 = (const float4*)x;
    float4 hnA[16], hnB[16];
#pragma unroll
    for (int s = 0; s < TC; s++) {
        size_t rb = (size_t)((c * TC + s) * NB + b) * (NH / 4);
        hnA[s] = x4[rb + lane];
        hnB[s] = x4[rb + 64 + lane];
    }
    const float4* s4 = (const float4*)src;
    for (int r = 0; r < 16; r++) {
        int p = p0 + r;
        size_t rowb = (size_t)(b * NP + p) * (NH / 4);
        float4 pvA = s4[rowb + lane];
        float4 pvB = s4[rowb + 64 + lane];
        float nrm = dot4(pvA, pvA) + dot4(pvB, pvB);
#pragma unroll
        for (int o = 32; o > 0; o >>= 1) nrm += __shfl_xor(nrm, o, 64);
        float inr = 1.0f / (sqrtf(nrm) + 1e-10f);
        float r0p[TC];
#pragma unroll
        for (int i = 0; i < TC; i++) r0p[i] = dot4(pvA, hnA[i]) + dot4(pvB, hnB[i]);
#pragma unroll
        for (int i = 0; i < TC; i++) scratch[w][i][lane] = r0p[i];
        int v = lane & 15, cq = lane >> 4;
        float part = 0.f;
#pragma unroll
        for (int j = 0; j < 16; j++) part += scratch[w][v][cq * 16 + j];
        part += __shfl_xor(part, 16, 64);
        part += __shfl_xor(part, 32, 64);
        if (lane < 16) R0[(size_t)(b * TC + v) * NP + p] = part * inr;
        if (lane == 0) inr_g[b * NP + p] = inr;
    }
}

// ---------------------------------------------------------------- kInner: serial 16-step solve only
__global__ __launch_bounds__(256, 1) void kInner(const float* __restrict__ R0, const float* __restrict__ G_all,
                                                 const float* __restrict__ inr_g, float* __restrict__ q_g,
                                                 float* __restrict__ wc_g, float* __restrict__ S_g,
                                                 float* __restrict__ Beta_g, int c) {
    int b = blockIdx.x, tid = threadIdx.x;
    int wid = tid >> 6, lane = tid & 63;
    __shared__ float Gs[TC * TC];
    __shared__ float redm[TC][4], reds[TC][4];
    __shared__ float betas[TC * TC];
    if (tid < TC * TC) {
        Gs[tid] = G_all[(size_t)(c * NB + b) * TC * TC + tid];
        betas[tid] = 0.f;
    }
    __syncthreads();
    const float* R0b = R0 + (size_t)b * TC * NP;
    float r0p[4][TC];
#pragma unroll
    for (int k = 0; k < 4; k++)
#pragma unroll
        for (int i = 0; i < TC; i++) r0p[k][i] = R0b[(size_t)i * NP + tid + 256 * k];

    float S[4] = {1.f, 1.f, 1.f, 1.f};
    float v[4][TC], q[4][TC];
    float raw[4];
#pragma unroll
    for (int i = 0; i < TC; i++) {
        float mymax = -1e30f;
#pragma unroll
        for (int k = 0; k < 4; k++) {
            float acc = r0p[k][i];
#pragma unroll
            for (int s = 0; s < i; s++) acc += v[k][s] * Gs[s * TC + i];
            raw[k] = S[k] * acc;
            mymax = fmaxf(mymax, raw[k]);
        }
#pragma unroll
        for (int o = 32; o > 0; o >>= 1) mymax = fmaxf(mymax, __shfl_xor(mymax, o, 64));
        if (lane == 0) redm[i][wid] = mymax;
        __syncthreads();
        float m = fmaxf(fmaxf(redm[i][0], redm[i][1]), fmaxf(redm[i][2], redm[i][3]));
        float hh = Gs[i * TC + i];
        float e[4], esum = 0.f;
#pragma unroll
        for (int k = 0; k < 4; k++) {
            float lg = (raw[k] >= 0.9f * m) ? (raw[k] / m) * 10.0f : 0.0f;
            e[k] = __expf(lg - 10.0f);
            esum += e[k];
        }
#pragma unroll
        for (int o = 32; o > 0; o >>= 1) esum += __shfl_xor(esum, o, 64);
        if (lane == 0) reds[i][wid] = esum;
        __syncthreads();
        float dinv = 1.0f / (reds[i][0] + reds[i][1] + reds[i][2] + reds[i][3]);
#pragma unroll
        for (int k = 0; k < 4; k++) {
            float pr = e[k] * dinv;
            q[k][i] = pr * S[k];
            float nn = sqrtf(DECAYF * DECAYF + 2.0f * DECAYF * pr * raw[k] + pr * pr * hh) + 1e-10f;
            v[k][i] = pr / (DECAYF * S[k]);
            S[k] = S[k] * (DECAYF / nn);
        }
    }
#pragma unroll
    for (int k = 0; k < 4; k++) {
        int p = tid + 256 * k;
        float inr = inr_g[b * NP + p];
        float4* qdst = (float4*)(q_g + (size_t)(b * NP + p) * TC);
        float4* wdst = (float4*)(wc_g + (size_t)(b * NP + p) * TC);
#pragma unroll
        for (int j = 0; j < 4; j++) {
            float4 tq, tw;
            tq.x = q[k][4 * j + 0] * inr; tq.y = q[k][4 * j + 1] * inr;
            tq.z = q[k][4 * j + 2] * inr; tq.w = q[k][4 * j + 3] * inr;
            tw.x = S[k] * v[k][4 * j + 0]; tw.y = S[k] * v[k][4 * j + 1];
            tw.z = S[k] * v[k][4 * j + 2]; tw.w = S[k] * v[k][4 * j + 3];
            qdst[j] = tq; wdst[j] = tw;
        }
        S_g[b * NP + p] = S[k] * inr;
    }
#pragma unroll
    for (int i = 1; i < TC; i++) {
#pragma unroll
        for (int s = 0; s < i; s++) {
            float prt = q[0][i] * v[0][s] + q[1][i] * v[1][s] + q[2][i] * v[2][s] + q[3][i] * v[3][s];
#pragma unroll
            for (int o = 32; o > 0; o >>= 1) prt += __shfl_xor(prt, o, 64);
            if (lane == 0) atomicAdd(&betas[i * TC + s], prt);
        }
    }
    __syncthreads();
    if (tid < TC * TC) {
        int i = tid / TC, s = tid % TC;
        Beta_g[(size_t)(c & 1) * NB * TC * TC + (size_t)b * TC * TC + tid] = (s < i) ? betas[tid] : 0.f;
    }
}

// ---------------------------------------------------------------- kStep: R9 two-pass body + fused outred(c-1)
// grid (NBLK + 16, NB). bx < NBLK: kStep proper. bx >= NBLK: outred(c-1)
// (reads part_r parity c-1 + Beta(c-1), writes out) riding in the shadow.
// redbuf ALIASES scratch (disjoint paths) so LDS stays 22016 (R11 lesson:
// +8KB LDS cut occupancy 25->16% and rate 3.3->2.2 TB/s).
template <int NBLK>
__global__ __launch_bounds__(256, 3) void kStep(float* __restrict__ pat, const float* __restrict__ patread,
                                                const float* __restrict__ x,
                                                const float* __restrict__ q_g, const float* __restrict__ wc_g,
                                                const float* __restrict__ S_g, float* __restrict__ R0,
                                                float* __restrict__ inr_g,
                                                float* __restrict__ part_w, const float* __restrict__ part_r,
                                                const float* __restrict__ Beta_g, float* __restrict__ out,
                                                int c, int do_upd) {
    constexpr int ROWS = NP / NBLK;
    int b = blockIdx.y, tid = threadIdx.x;
    int w = tid >> 6, lane = tid & 63;
    __shared__ __align__(16) float wcs[ROWS][20];          // wc(16)+Sf
    __shared__ __align__(16) float scratch[4][16][65];     // 16.6 KB: r0 transpose-reduce
    float4 (*redbuf)[128] = (float4 (*)[128])&scratch[0][0][0];  // alias: outred-only (8.2KB <= 16.6KB)

    if (blockIdx.x >= NBLK) {
        // ---- outred path: chunk c-1, i = bx - NBLK ----
        if (c == 0) return;
        int cc = c - 1;
        int i = blockIdx.x - NBLK;
        const float4* part4 = (const float4*)part_r;
        float4 sumA = make_float4(0.f, 0.f, 0.f, 0.f), sumB = make_float4(0.f, 0.f, 0.f, 0.f);
        constexpr int PER = NBLK / 4;
        for (int t = 0; t < PER; t++) {
            int blk = w * PER + t;
            size_t base = ((((size_t)blk * NB + b) * TC) + i) * (NH / 4);
            add4(sumA, part4[base + lane]);
            add4(sumB, part4[base + 64 + lane]);
        }
        redbuf[w][lane] = sumA;
        redbuf[w][64 + lane] = sumB;
        __syncthreads();
        if (w == 0) {
            float4 sA = redbuf[0][lane], sB = redbuf[0][64 + lane];
            add4(sA, redbuf[1][lane]); add4(sB, redbuf[1][64 + lane]);
            add4(sA, redbuf[2][lane]); add4(sB, redbuf[2][64 + lane]);
            add4(sA, redbuf[3][lane]); add4(sB, redbuf[3][64 + lane]);
            const float4* x4 = (const float4*)x;
            const float* Bb = Beta_g + (size_t)(cc & 1) * NB * TC * TC + (size_t)b * TC * TC + i * TC;
#pragma unroll
            for (int s = 0; s < TC - 1; s++) {
                if (s < i) {
                    float beta = Bb[s];
                    size_t rb = (size_t)((cc * TC + s) * NB + b) * (NH / 4);
                    fma4(sA, beta, x4[rb + lane]);
                    fma4(sB, beta, x4[rb + 64 + lane]);
                }
            }
            size_t ob = (size_t)((cc * TC + i) * NB + b) * (NH / 4);
            ((float4*)out)[ob + lane] = sA;
            ((float4*)out)[ob + 64 + lane] = sB;
        }
        return;
    }

    int pbase = blockIdx.x * ROWS;
    if (do_upd) {
        const float4* wcg4 = (const float4*)(wc_g + (size_t)(b * NP + pbase) * TC);
        for (int idx = tid; idx < ROWS * 4; idx += 256) {
            float4 vv = wcg4[idx];
            *(float4*)&wcs[idx >> 2][(idx & 3) * 4] = vv;
        }
        for (int idx = tid; idx < ROWS; idx += 256) wcs[idx][16] = S_g[b * NP + pbase + idx];
    }

    // ---- sweep 1: out partials (8-row unroll, grouped loads) ----
    const float4* p4c = (const float4*)patread;
    float4 accA[4], accB[4];
#pragma unroll
    for (int j = 0; j < 4; j++) { accA[j] = make_float4(0.f, 0.f, 0.f, 0.f); accB[j] = make_float4(0.f, 0.f, 0.f, 0.f); }
    for (int rq = 0; rq < ROWS; rq += 8) {
        float4 pvA[8], pvB[8], qv[8];
#pragma unroll
        for (int u = 0; u < 8; u++) {
            int p = pbase + rq + u;
            size_t rowb = (size_t)(b * NP + p) * (NH / 4);
            pvA[u] = p4c[rowb + lane];
            pvB[u] = p4c[rowb + 64 + lane];
            qv[u] = *(const float4*)(q_g + (size_t)(b * NP + p) * TC + w * 4);
        }
#pragma unroll
        for (int u = 0; u < 8; u++) {
            fma4(accA[0], qv[u].x, pvA[u]); fma4(accB[0], qv[u].x, pvB[u]);
            fma4(accA[1], qv[u].y, pvA[u]); fma4(accB[1], qv[u].y, pvB[u]);
            fma4(accA[2], qv[u].z, pvA[u]); fma4(accB[2], qv[u].z, pvB[u]);
            fma4(accA[3], qv[u].w, pvA[u]); fma4(accB[3], qv[u].w, pvB[u]);
        }
    }
    float4* part4w = (float4*)part_w;
#pragma unroll
    for (int j = 0; j < 4; j++) {
        size_t pb = ((((size_t)blockIdx.x * NB + b) * TC) + (w * 4 + j)) * (NH / 4);
        part4w[pb + lane] = accA[j];
        part4w[pb + 64 + lane] = accB[j];
    }

    __syncthreads();  // all reads of pat rows done; LDS staging visible
    if (!do_upd) return;

    // ---- pass A: update + write + nrm (hc L1-resident) ----
    const float4* x4 = (const float4*)x;
    float4 hA[16], hB[16];
#pragma unroll
    for (int s = 0; s < TC; s++) {
        size_t rb = (size_t)((c * TC + s) * NB + b) * (NH / 4);
        hA[s] = x4[rb + lane];
        hB[s] = x4[rb + 64 + lane];
    }
    float4* p4 = (float4*)pat;
    for (int r = 0; r < ROWS / 4; r++) {
        int rr = w * (ROWS / 4) + r;
        int p = pbase + rr;
        size_t rowb = (size_t)(b * NP + p) * (NH / 4);
        float4 pvA = p4c[rowb + lane];
        float4 pvB = p4c[rowb + 64 + lane];
        float4 w0 = *(float4*)&wcs[rr][0];
        float4 w1 = *(float4*)&wcs[rr][4];
        float4 w2 = *(float4*)&wcs[rr][8];
        float4 w3 = *(float4*)&wcs[rr][12];
        float Sf = wcs[rr][16];
        float wcv[16] = {w0.x, w0.y, w0.z, w0.w, w1.x, w1.y, w1.z, w1.w,
                         w2.x, w2.y, w2.z, w2.w, w3.x, w3.y, w3.z, w3.w};
        float4 pnA, pnB;
        pnA.x = Sf * pvA.x; pnA.y = Sf * pvA.y; pnA.z = Sf * pvA.z; pnA.w = Sf * pvA.w;
        pnB.x = Sf * pvB.x; pnB.y = Sf * pvB.y; pnB.z = Sf * pvB.z; pnB.w = Sf * pvB.w;
#pragma unroll
        for (int s = 0; s < TC; s++) {
            fma4(pnA, wcv[s], hA[s]);
            fma4(pnB, wcv[s], hB[s]);
        }
        p4[rowb + lane] = pnA;
        p4[rowb + 64 + lane] = pnB;
        float nrm = dot4(pnA, pnA) + dot4(pnB, pnB);
#pragma unroll
        for (int o = 32; o > 0; o >>= 1) nrm += __shfl_xor(nrm, o, 64);
        float inr = 1.0f / (sqrtf(nrm) + 1e-10f);
        if (lane == 0) inr_g[b * NP + p] = inr;
    }

    // ---- pass B: r0 vs next chunk (hn L1-resident; pn re-read L2-hot) ----
#pragma unroll
    for (int s = 0; s < TC; s++) {
        size_t rb = (size_t)(((c + 1) * TC + s) * NB + b) * (NH / 4);
        hA[s] = x4[rb + lane];
        hB[s] = x4[rb + 64 + lane];
    }
    for (int r = 0; r < ROWS / 4; r++) {
        int rr = w * (ROWS / 4) + r;
        int p = pbase + rr;
        size_t rowb = (size_t)(b * NP + p) * (NH / 4);
        float4 pnA = p4[rowb + lane];
        float4 pnB = p4[rowb + 64 + lane];
        float inr = inr_g[b * NP + p];
        float r0p[TC];
#pragma unroll
        for (int i = 0; i < TC; i++) r0p[i] = dot4(pnA, hA[i]) + dot4(pnB, hB[i]);
#pragma unroll
        for (int i = 0; i < TC; i++) scratch[w][i][lane] = r0p[i];
        int v = lane & 15, cq = lane >> 4;
        float ps = 0.f;
#pragma unroll
        for (int j = 0; j < 16; j++) ps += scratch[w][v][cq * 16 + j];
        ps += __shfl_xor(ps, 16, 64);
        ps += __shfl_xor(ps, 32, 64);
        if (lane < 16) R0[(size_t)(b * TC + v) * NP + p] = ps * inr;
    }
}

// ---------------------------------------------------------------- kOutRed: standalone for the last chunk
__global__ __launch_bounds__(256) void kOutRed(const float* __restrict__ part, const float* __restrict__ x,
                                               const float* __restrict__ Beta_g, float* __restrict__ out,
                                               int npb, int c) {
    int b = blockIdx.y, i = blockIdx.x, tid = threadIdx.x;
    int wid = tid >> 6, lane = tid & 63;
    __shared__ float4 redbuf[4][128];
    const float4* part4 = (const float4*)part;
    float4 sumA = make_float4(0.f, 0.f, 0.f, 0.f), sumB = make_float4(0.f, 0.f, 0.f, 0.f);
    int per = npb >> 2;
    for (int t = 0; t < per; t++) {
        int blk = wid * per + t;
        size_t base = ((((size_t)blk * NB + b) * TC) + i) * (NH / 4);
        add4(sumA, part4[base + lane]);
        add4(sumB, part4[base + 64 + lane]);
    }
    redbuf[wid][lane] = sumA;
    redbuf[wid][64 + lane] = sumB;
    __syncthreads();
    if (wid == 0) {
        float4 sA = redbuf[0][lane], sB = redbuf[0][64 + lane];
        add4(sA, redbuf[1][lane]); add4(sB, redbuf[1][64 + lane]);
        add4(sA, redbuf[2][lane]); add4(sB, redbuf[2][64 + lane]);
        add4(sA, redbuf[3][lane]); add4(sB, redbuf[3][64 + lane]);
        const float4* x4 = (const float4*)x;
        const float* Bb = Beta_g + (size_t)b * TC * TC + i * TC;
#pragma unroll
        for (int s = 0; s < TC - 1; s++) {
            if (s < i) {
                float beta = Bb[s];
                size_t rb = (size_t)((c * TC + s) * NB + b) * (NH / 4);
                fma4(sA, beta, x4[rb + lane]);
                fma4(sB, beta, x4[rb + 64 + lane]);
            }
        }
        size_t ob = (size_t)((c * TC + i) * NB + b) * (NH / 4);
        ((float4*)out)[ob + lane] = sA;
        ((float4*)out)[ob + 64 + lane] = sB;
    }
}

// ---------------------------------------------------------------- launch
extern "C" void kernel_launch(void* const* d_in, const int* in_sizes, int n_in,
                              void* d_out, int out_size, void* d_ws, size_t ws_size,
                              hipStream_t stream) {
    const float* x = (const float*)d_in[0];      // [T,B,H]
    const float* patin = (const float*)d_in[1];  // [B,P,H]
    float* out = (float*)d_out;                  // [T,B,H]

    char* ws = (char*)d_ws;
    size_t off = 0;
    auto alloc = [&](size_t nfloats) { float* r = (float*)(ws + off); off += nfloats * sizeof(float); return r; };

    // fixed small buffers (~13.8 MB)
    float* R0 = alloc((size_t)NB * TC * NP);
    float* q_g = alloc((size_t)NB * TC * NP);
    float* wc_g = alloc((size_t)NB * TC * NP);
    float* S_g = alloc((size_t)NB * NP);
    float* inr_g = alloc((size_t)NB * NP);
    float* G_all = alloc((size_t)NCH * NB * TC * TC);
    float* Beta = alloc((size_t)2 * NB * TC * TC);  // parity double-buffered

    // part: parity double-buffered (fused outred reads c-1 while kStep writes c)
    const size_t partUnit = (size_t)NB * TC * NH;   // floats per p-block
    const size_t patN = (size_t)NB * NP * NH;
    int nblk;
    if (ws_size >= off + (2 * 16 * partUnit + patN) * sizeof(float)) nblk = 16;
    else nblk = 8;
    const size_t partN = (size_t)nblk * partUnit;
    float* part0 = alloc(partN);
    float* part1 = alloc(partN);

    // pat: workspace if it fits, else in-place (harness restores input per launch)
    float* pat;
    if (ws_size >= off + patN * sizeof(float)) {
        pat = alloc(patN);
    } else {
        pat = (float*)d_in[1];
    }

    kG<<<dim3(NCH, NB), 256, 0, stream>>>(x, G_all);
    kPatR0<<<dim3(16, NB), 256, 0, stream>>>(patin, x, R0, inr_g, 0);
    for (int c = 0; c < NCH; c++) {
        kInner<<<NB, 256, 0, stream>>>(R0, G_all, inr_g, q_g, wc_g, S_g, Beta, c);
        int du = (c + 1 < NCH) ? 1 : 0;
        float* pw = (c & 1) ? part1 : part0;
        const float* pr = (c & 1) ? part0 : part1;   // parity c-1
        const float* patread = (c == 0) ? patin : pat;
        if (nblk == 16)
            kStep<16><<<dim3(32, NB), 256, 0, stream>>>(pat, patread, x, q_g, wc_g, S_g, R0, inr_g,
                                                        pw, pr, Beta, out, c, du);
        else
            kStep<8><<<dim3(24, NB), 256, 0, stream>>>(pat, patread, x, q_g, wc_g, S_g, R0, inr_g,
                                                       pw, pr, Beta, out, c, du);
    }
    const float* lastPart = ((NCH - 1) & 1) ? part1 : part0;
    kOutRed<<<dim3(16, NB), 256, 0, stream>>>(lastPart, x, Beta + (size_t)((NCH - 1) & 1) * NB * TC * TC,
                                              out, nblk, NCH - 1);
}

// Round 13
// 2841.756 us; speedup vs baseline: 1.4410x; 1.2614x over previous
//
#include <hip/hip_runtime.h>
#include <math.h>

// GnrlPatSoftmaxRNN: chunked low-rank reformulation.
// pat_t = S_t[p]*pat_t0[p,:] + S_t[p]*sum_s v_s[p]*h_s[:], analytic norm.
// Proven constraints (do not violate):
//   - launch_bounds(256,3) for kStep ((256,6) caps VGPR@40 -> spill: R3).
//   - hc and hn must not stream together through L1 (64KB>32KB L1: R5).
//   - two-pass sweep2 IS the L1 blocking; keep it (R5/R6).
//   - kStep phase structure is a LOCAL OPTIMUM: merge (R5), tile-fuse (R7),
//     granule-split (R10) all lost. Do not restructure.
//   - kStep must run ALONE in its dispatch window: outred riders mixed in
//     (R11/R12) collapse rate 3.3->2.2 TB/s regardless of LDS/occupancy
//     bookkeeping. Foreign streams poison the phased pat streaming.
// Best proven: R9/R13 structure = 2846us (kStep 122us standalone +
//   kInnerOut(17,NB): solve in bx==0, outred(c-1) rides behind the
//   LATENCY-bound solve, not the BW-bound kStep).
// R17 (this): R9 structure + the one orthogonal R11 win: kPatR0 no longer
//   copies pat (134MB write deleted); kStep reads patin directly at c=0
//   via patread pointer and writes ws pat.

#define T_TOT 256
#define NB    64
#define NP    1024
#define NH    512
#define TC    16
#define NCH   (T_TOT / TC)
#define DECAYF 0.999f

__device__ __forceinline__ float dot4(float4 a, float4 b) {
    return a.x * b.x + a.y * b.y + a.z * b.z + a.w * b.w;
}
__device__ __forceinline__ void fma4(float4& acc, float s, float4 v) {
    acc.x += s * v.x; acc.y += s * v.y; acc.z += s * v.z; acc.w += s * v.w;
}
__device__ __forceinline__ void add4(float4& acc, float4 v) {
    acc.x += v.x; acc.y += v.y; acc.z += v.z; acc.w += v.w;
}

// ---------------------------------------------------------------- kG: Gram per chunk
__global__ __launch_bounds__(256) void kG(const float* __restrict__ x, float* __restrict__ G_all) {
    int c = blockIdx.x, b = blockIdx.y, tid = threadIdx.x;
    __shared__ float4 hs[TC][NH / 4 + 1];
    for (int idx = tid; idx < TC * (NH / 4); idx += 256) {
        int s = idx / (NH / 4), g = idx % (NH / 4);
        hs[s][g] = ((const float4*)x)[(size_t)((c * TC + s) * NB + b) * (NH / 4) + g];
    }
    __syncthreads();
    int si = tid / TC, ii = tid % TC;
    float acc = 0.f;
    for (int g = 0; g < NH / 4; g++) acc += dot4(hs[si][g], hs[ii][g]);
    G_all[(size_t)((c * NB + b) * TC + si) * TC + ii] = acc;
}

// ---------------------------------------------------------------- kPatR0: nrm + R0 for chunk 0 (no copy)
__global__ __launch_bounds__(256) void kPatR0(const float* __restrict__ src,
                                              const float* __restrict__ x, float* __restrict__ R0,
                                              float* __restrict__ inr_g, int c) {
    int b = blockIdx.y, tid = threadIdx.x;
    int w = tid >> 6, lane = tid & 63;
    int p0 = blockIdx.x * 64 + w * 16;
    __shared__ float scratch[4][16][65];
    const float4* x4 = (const float4*)x;
    float4 hnA[16], hnB[16];
#pragma unroll
    for (int s = 0; s < TC; s++) {
        size_t rb = (size_t)((c * TC + s) * NB + b) * (NH / 4);
        hnA[s] = x4[rb + lane];
        hnB[s] = x4[rb + 64 + lane];
    }
    const float4* s4 = (const float4*)src;
    for (int r = 0; r < 16; r++) {
        int p = p0 + r;
        size_t rowb = (size_t)(b * NP + p) * (NH / 4);
        float4 pvA = s4[rowb + lane];
        float4 pvB = s4[rowb + 64 + lane];
        float nrm = dot4(pvA, pvA) + dot4(pvB, pvB);
#pragma unroll
        for (int o = 32; o > 0; o >>= 1) nrm += __shfl_xor(nrm, o, 64);
        float inr = 1.0f / (sqrtf(nrm) + 1e-10f);
        float r0p[TC];
#pragma unroll
        for (int i = 0; i < TC; i++) r0p[i] = dot4(pvA, hnA[i]) + dot4(pvB, hnB[i]);
#pragma unroll
        for (int i = 0; i < TC; i++) scratch[w][i][lane] = r0p[i];
        int v = lane & 15, cq = lane >> 4;
        float part = 0.f;
#pragma unroll
        for (int j = 0; j < 16; j++) part += scratch[w][v][cq * 16 + j];
        part += __shfl_xor(part, 16, 64);
        part += __shfl_xor(part, 32, 64);
        if (lane < 16) R0[(size_t)(b * TC + v) * NP + p] = part * inr;
        if (lane == 0) inr_g[b * NP + p] = inr;
    }
}

// ---------------------------------------------------------------- kInnerOut: kInner(c) + kOutRed(c-1)
// grid (17, NB). bx==0: serial 16-step inner solve for chunk c.
// bx in 1..16: out-reduction for chunk c-1, ONE i per block, 4 waves split
// the npb partial-blocks, LDS cross-wave reduce. Rides behind the
// LATENCY-bound solve (NOT inside kStep -- R11/R12 lesson).
__global__ __launch_bounds__(256, 1) void kInnerOut(const float* __restrict__ R0, const float* __restrict__ G_all,
                                                    const float* __restrict__ inr_g, float* __restrict__ q_g,
                                                    float* __restrict__ wc_g, float* __restrict__ S_g,
                                                    float* __restrict__ Beta_g,
                                                    const float* __restrict__ part, const float* __restrict__ x,
                                                    float* __restrict__ out, int npb, int c) {
    int b = blockIdx.y, tid = threadIdx.x;
    int wid = tid >> 6, lane = tid & 63;
    __shared__ float Gs[TC * TC];
    __shared__ float redm[TC][4], reds[TC][4];
    __shared__ float betas[TC * TC];
    __shared__ float4 redbuf[4][128];

    if (blockIdx.x != 0) {
        // ---- kOutRed path: chunk c-1, i = blockIdx.x-1 ----
        if (c == 0) return;
        int cc = c - 1;
        int i = blockIdx.x - 1;
        const float4* part4 = (const float4*)part;
        float4 sumA = make_float4(0.f, 0.f, 0.f, 0.f), sumB = make_float4(0.f, 0.f, 0.f, 0.f);
        int per = npb >> 2;  // partial-blocks per wave
        for (int t = 0; t < per; t++) {
            int blk = wid * per + t;
            size_t base = ((((size_t)blk * NB + b) * TC) + i) * (NH / 4);
            add4(sumA, part4[base + lane]);
            add4(sumB, part4[base + 64 + lane]);
        }
        redbuf[wid][lane] = sumA;
        redbuf[wid][64 + lane] = sumB;
        __syncthreads();
        if (wid == 0) {
            float4 sA = redbuf[0][lane], sB = redbuf[0][64 + lane];
            add4(sA, redbuf[1][lane]); add4(sB, redbuf[1][64 + lane]);
            add4(sA, redbuf[2][lane]); add4(sB, redbuf[2][64 + lane]);
            add4(sA, redbuf[3][lane]); add4(sB, redbuf[3][64 + lane]);
            const float4* x4 = (const float4*)x;
            const float* Bb = Beta_g + (size_t)(cc & 1) * NB * TC * TC + (size_t)b * TC * TC + i * TC;
#pragma unroll
            for (int s = 0; s < TC - 1; s++) {
                if (s < i) {
                    float beta = Bb[s];
                    size_t rb = (size_t)((cc * TC + s) * NB + b) * (NH / 4);
                    fma4(sA, beta, x4[rb + lane]);
                    fma4(sB, beta, x4[rb + 64 + lane]);
                }
            }
            size_t ob = (size_t)((cc * TC + i) * NB + b) * (NH / 4);
            ((float4*)out)[ob + lane] = sA;
            ((float4*)out)[ob + 64 + lane] = sB;
        }
        return;
    }

    // ---- kInner path: chunk c ----
    if (tid < TC * TC) {
        Gs[tid] = G_all[(size_t)(c * NB + b) * TC * TC + tid];
        betas[tid] = 0.f;
    }
    __syncthreads();
    const float* R0b = R0 + (size_t)b * TC * NP;
    float r0p[4][TC];
#pragma unroll
    for (int k = 0; k < 4; k++)
#pragma unroll
        for (int i = 0; i < TC; i++) r0p[k][i] = R0b[(size_t)i * NP + tid + 256 * k];

    float S[4] = {1.f, 1.f, 1.f, 1.f};
    float v[4][TC], q[4][TC];
    float raw[4];
#pragma unroll
    for (int i = 0; i < TC; i++) {
        float mymax = -1e30f;
#pragma unroll
        for (int k = 0; k < 4; k++) {
            float acc = r0p[k][i];
#pragma unroll
            for (int s = 0; s < i; s++) acc += v[k][s] * Gs[s * TC + i];
            raw[k] = S[k] * acc;
            mymax = fmaxf(mymax, raw[k]);
        }
#pragma unroll
        for (int o = 32; o > 0; o >>= 1) mymax = fmaxf(mymax, __shfl_xor(mymax, o, 64));
        if (lane == 0) redm[i][wid] = mymax;
        __syncthreads();
        float m = fmaxf(fmaxf(redm[i][0], redm[i][1]), fmaxf(redm[i][2], redm[i][3]));
        float hh = Gs[i * TC + i];
        float e[4], esum = 0.f;
#pragma unroll
        for (int k = 0; k < 4; k++) {
            float lg = (raw[k] >= 0.9f * m) ? (raw[k] / m) * 10.0f : 0.0f;
            e[k] = __expf(lg - 10.0f);
            esum += e[k];
        }
#pragma unroll
        for (int o = 32; o > 0; o >>= 1) esum += __shfl_xor(esum, o, 64);
        if (lane == 0) reds[i][wid] = esum;
        __syncthreads();
        float dinv = 1.0f / (reds[i][0] + reds[i][1] + reds[i][2] + reds[i][3]);
#pragma unroll
        for (int k = 0; k < 4; k++) {
            float pr = e[k] * dinv;
            q[k][i] = pr * S[k];
            float nn = sqrtf(DECAYF * DECAYF + 2.0f * DECAYF * pr * raw[k] + pr * pr * hh) + 1e-10f;
            v[k][i] = pr / (DECAYF * S[k]);
            S[k] = S[k] * (DECAYF / nn);
        }
    }
#pragma unroll
    for (int k = 0; k < 4; k++) {
        int p = tid + 256 * k;
        float inr = inr_g[b * NP + p];
        float4* qdst = (float4*)(q_g + (size_t)(b * NP + p) * TC);
        float4* wdst = (float4*)(wc_g + (size_t)(b * NP + p) * TC);
#pragma unroll
        for (int j = 0; j < 4; j++) {
            float4 tq, tw;
            tq.x = q[k][4 * j + 0] * inr; tq.y = q[k][4 * j + 1] * inr;
            tq.z = q[k][4 * j + 2] * inr; tq.w = q[k][4 * j + 3] * inr;
            tw.x = S[k] * v[k][4 * j + 0]; tw.y = S[k] * v[k][4 * j + 1];
            tw.z = S[k] * v[k][4 * j + 2]; tw.w = S[k] * v[k][4 * j + 3];
            qdst[j] = tq; wdst[j] = tw;
        }
        S_g[b * NP + p] = S[k] * inr;
    }
#pragma unroll
    for (int i = 1; i < TC; i++) {
#pragma unroll
        for (int s = 0; s < i; s++) {
            float prt = q[0][i] * v[0][s] + q[1][i] * v[1][s] + q[2][i] * v[2][s] + q[3][i] * v[3][s];
#pragma unroll
            for (int o = 32; o > 0; o >>= 1) prt += __shfl_xor(prt, o, 64);
            if (lane == 0) atomicAdd(&betas[i * TC + s], prt);
        }
    }
    __syncthreads();
    if (tid < TC * TC) {
        int i = tid / TC, s = tid % TC;
        Beta_g[(size_t)(c & 1) * NB * TC * TC + (size_t)b * TC * TC + tid] = (s < i) ? betas[tid] : 0.f;
    }
}

// ---------------------------------------------------------------- kStep: two-pass body (R9-proven), standalone
// grid (NBLK, NB), block 256. Block owns ROWS = NP/NBLK pat rows.
// Sweep1: every wave reads all ROWS rows (8-row unrolled), accumulates
//   out-partials for its 4 i-values, writes part. Barrier.
// Sweep2 (do_upd), TWO passes per wave over its ROWS/4 rows:
//   pass A: hc (32KB, L1-resident); pn = Sf*pv + sum wc*hc; write pat; nrm.
//   pass B: hn (32KB, L1-resident); pn re-read (L2-hot); r0 -> R0.
// DO NOT merge A+B (R5). DO NOT raise launch bound (R3). DO NOT add rider
// blocks (R11/R12). patread != pat only at c==0 (reads pristine patin).
template <int NBLK>
__global__ __launch_bounds__(256, 3) void kStep(float* __restrict__ pat, const float* __restrict__ patread,
                                                const float* __restrict__ x,
                                                const float* __restrict__ q_g, const float* __restrict__ wc_g,
                                                const float* __restrict__ S_g, float* __restrict__ R0,
                                                float* __restrict__ inr_g, float* __restrict__ part,
                                                int c, int do_upd) {
    constexpr int ROWS = NP / NBLK;
    int b = blockIdx.y, tid = threadIdx.x;
    int w = tid >> 6, lane = tid & 63;
    int pbase = blockIdx.x * ROWS;
    __shared__ __align__(16) float wcs[ROWS][20]; // wc(16)+Sf
    __shared__ float scratch[4][16][65];          // 16.6 KB: r0 transpose-reduce

    if (do_upd) {
        const float4* wcg4 = (const float4*)(wc_g + (size_t)(b * NP + pbase) * TC);
        for (int idx = tid; idx < ROWS * 4; idx += 256) {
            float4 vv = wcg4[idx];
            *(float4*)&wcs[idx >> 2][(idx & 3) * 4] = vv;
        }
        for (int idx = tid; idx < ROWS; idx += 256) wcs[idx][16] = S_g[b * NP + pbase + idx];
    }

    // ---- sweep 1: out partials (8-row unroll, grouped loads) ----
    const float4* p4c = (const float4*)patread;
    float4 accA[4], accB[4];
#pragma unroll
    for (int j = 0; j < 4; j++) { accA[j] = make_float4(0.f, 0.f, 0.f, 0.f); accB[j] = make_float4(0.f, 0.f, 0.f, 0.f); }
    for (int rq = 0; rq < ROWS; rq += 8) {
        float4 pvA[8], pvB[8], qv[8];
#pragma unroll
        for (int u = 0; u < 8; u++) {
            int p = pbase + rq + u;
            size_t rowb = (size_t)(b * NP + p) * (NH / 4);
            pvA[u] = p4c[rowb + lane];
            pvB[u] = p4c[rowb + 64 + lane];
            qv[u] = *(const float4*)(q_g + (size_t)(b * NP + p) * TC + w * 4);
        }
#pragma unroll
        for (int u = 0; u < 8; u++) {
            fma4(accA[0], qv[u].x, pvA[u]); fma4(accB[0], qv[u].x, pvB[u]);
            fma4(accA[1], qv[u].y, pvA[u]); fma4(accB[1], qv[u].y, pvB[u]);
            fma4(accA[2], qv[u].z, pvA[u]); fma4(accB[2], qv[u].z, pvB[u]);
            fma4(accA[3], qv[u].w, pvA[u]); fma4(accB[3], qv[u].w, pvB[u]);
        }
    }
    float4* part4 = (float4*)part;
#pragma unroll
    for (int j = 0; j < 4; j++) {
        size_t pb = ((((size_t)blockIdx.x * NB + b) * TC) + (w * 4 + j)) * (NH / 4);
        part4[pb + lane] = accA[j];
        part4[pb + 64 + lane] = accB[j];
    }

    __syncthreads();  // all reads of pat rows done; LDS staging visible
    if (!do_upd) return;

    // ---- pass A: update + write + nrm (hc L1-resident) ----
    const float4* x4 = (const float4*)x;
    float4 hA[16], hB[16];
#pragma unroll
    for (int s = 0; s < TC; s++) {
        size_t rb = (size_t)((c * TC + s) * NB + b) * (NH / 4);
        hA[s] = x4[rb + lane];
        hB[s] = x4[rb + 64 + lane];
    }
    float4* p4 = (float4*)pat;
    for (int r = 0; r < ROWS / 4; r++) {
        int rr = w * (ROWS / 4) + r;
        int p = pbase + rr;
        size_t rowb = (size_t)(b * NP + p) * (NH / 4);
        float4 pvA = p4c[rowb + lane];
        float4 pvB = p4c[rowb + 64 + lane];
        float4 w0 = *(float4*)&wcs[rr][0];
        float4 w1 = *(float4*)&wcs[rr][4];
        float4 w2 = *(float4*)&wcs[rr][8];
        float4 w3 = *(float4*)&wcs[rr][12];
        float Sf = wcs[rr][16];
        float wcv[16] = {w0.x, w0.y, w0.z, w0.w, w1.x, w1.y, w1.z, w1.w,
                         w2.x, w2.y, w2.z, w2.w, w3.x, w3.y, w3.z, w3.w};
        float4 pnA, pnB;
        pnA.x = Sf * pvA.x; pnA.y = Sf * pvA.y; pnA.z = Sf * pvA.z; pnA.w = Sf * pvA.w;
        pnB.x = Sf * pvB.x; pnB.y = Sf * pvB.y; pnB.z = Sf * pvB.z; pnB.w = Sf * pvB.w;
#pragma unroll
        for (int s = 0; s < TC; s++) {
            fma4(pnA, wcv[s], hA[s]);
            fma4(pnB, wcv[s], hB[s]);
        }
        p4[rowb + lane] = pnA;
        p4[rowb + 64 + lane] = pnB;
        float nrm = dot4(pnA, pnA) + dot4(pnB, pnB);
#pragma unroll
        for (int o = 32; o > 0; o >>= 1) nrm += __shfl_xor(nrm, o, 64);
        float inr = 1.0f / (sqrtf(nrm) + 1e-10f);
        if (lane == 0) inr_g[b * NP + p] = inr;
    }

    // ---- pass B: r0 vs next chunk (hn L1-resident; pn re-read L2-hot) ----
#pragma unroll
    for (int s = 0; s < TC; s++) {
        size_t rb = (size_t)(((c + 1) * TC + s) * NB + b) * (NH / 4);
        hA[s] = x4[rb + lane];
        hB[s] = x4[rb + 64 + lane];
    }
    for (int r = 0; r < ROWS / 4; r++) {
        int rr = w * (ROWS / 4) + r;
        int p = pbase + rr;
        size_t rowb = (size_t)(b * NP + p) * (NH / 4);
        float4 pnA = p4[rowb + lane];
        float4 pnB = p4[rowb + 64 + lane];
        float inr = inr_g[b * NP + p];
        float r0p[TC];
#pragma unroll
        for (int i = 0; i < TC; i++) r0p[i] = dot4(pnA, hA[i]) + dot4(pnB, hB[i]);
#pragma unroll
        for (int i = 0; i < TC; i++) scratch[w][i][lane] = r0p[i];
        int v = lane & 15, cq = lane >> 4;
        float ps = 0.f;
#pragma unroll
        for (int j = 0; j < 16; j++) ps += scratch[w][v][cq * 16 + j];
        ps += __shfl_xor(ps, 16, 64);
        ps += __shfl_xor(ps, 32, 64);
        if (lane < 16) R0[(size_t)(b * TC + v) * NP + p] = ps * inr;
    }
}

// ---------------------------------------------------------------- kOutRed: standalone for the last chunk
// grid (16, NB): ONE i per block, 4 waves split npb partials.
__global__ __launch_bounds__(256) void kOutRed(const float* __restrict__ part, const float* __restrict__ x,
                                               const float* __restrict__ Beta_g, float* __restrict__ out,
                                               int npb, int c) {
    int b = blockIdx.y, i = blockIdx.x, tid = threadIdx.x;
    int wid = tid >> 6, lane = tid & 63;
    __shared__ float4 redbuf[4][128];
    const float4* part4 = (const float4*)part;
    float4 sumA = make_float4(0.f, 0.f, 0.f, 0.f), sumB = make_float4(0.f, 0.f, 0.f, 0.f);
    int per = npb >> 2;
    for (int t = 0; t < per; t++) {
        int blk = wid * per + t;
        size_t base = ((((size_t)blk * NB + b) * TC) + i) * (NH / 4);
        add4(sumA, part4[base + lane]);
        add4(sumB, part4[base + 64 + lane]);
    }
    redbuf[wid][lane] = sumA;
    redbuf[wid][64 + lane] = sumB;
    __syncthreads();
    if (wid == 0) {
        float4 sA = redbuf[0][lane], sB = redbuf[0][64 + lane];
        add4(sA, redbuf[1][lane]); add4(sB, redbuf[1][64 + lane]);
        add4(sA, redbuf[2][lane]); add4(sB, redbuf[2][64 + lane]);
        add4(sA, redbuf[3][lane]); add4(sB, redbuf[3][64 + lane]);
        const float4* x4 = (const float4*)x;
        const float* Bb = Beta_g + (size_t)b * TC * TC + i * TC;
#pragma unroll
        for (int s = 0; s < TC - 1; s++) {
            if (s < i) {
                float beta = Bb[s];
                size_t rb = (size_t)((c * TC + s) * NB + b) * (NH / 4);
                fma4(sA, beta, x4[rb + lane]);
                fma4(sB, beta, x4[rb + 64 + lane]);
            }
        }
        size_t ob = (size_t)((c * TC + i) * NB + b) * (NH / 4);
        ((float4*)out)[ob + lane] = sA;
        ((float4*)out)[ob + 64 + lane] = sB;
    }
}

// ---------------------------------------------------------------- launch
extern "C" void kernel_launch(void* const* d_in, const int* in_sizes, int n_in,
                              void* d_out, int out_size, void* d_ws, size_t ws_size,
                              hipStream_t stream) {
    const float* x = (const float*)d_in[0];      // [T,B,H]
    const float* patin = (const float*)d_in[1];  // [B,P,H]
    float* out = (float*)d_out;                  // [T,B,H]

    char* ws = (char*)d_ws;
    size_t off = 0;
    auto alloc = [&](size_t nfloats) { float* r = (float*)(ws + off); off += nfloats * sizeof(float); return r; };

    // fixed small buffers (~13.8 MB)
    float* R0 = alloc((size_t)NB * TC * NP);
    float* q_g = alloc((size_t)NB * TC * NP);
    float* wc_g = alloc((size_t)NB * TC * NP);
    float* S_g = alloc((size_t)NB * NP);
    float* inr_g = alloc((size_t)NB * NP);
    float* G_all = alloc((size_t)NCH * NB * TC * TC);
    float* Beta = alloc((size_t)2 * NB * TC * TC);  // parity double-buffered (kInnerOut(c) writes c, reads c-1)

    // part: single buffer (stream-ordered: outred(c-1) in kInnerOut(c)
    // completes before kStep(c) rewrites part)
    const size_t partUnit = (size_t)NB * TC * NH;   // floats per p-block
    int nblk;
    if (ws_size >= off + 16 * partUnit * sizeof(float)) nblk = 16;
    else nblk = 8;
    float* part = alloc((size_t)nblk * partUnit);

    // pat: workspace if it fits, else in-place (harness restores input per launch)
    const size_t patN = (size_t)NB * NP * NH;
    float* pat;
    if (ws_size >= off + patN * sizeof(float)) {
        pat = alloc(patN);
    } else {
        pat = (float*)d_in[1];
    }

    kG<<<dim3(NCH, NB), 256, 0, stream>>>(x, G_all);
    kPatR0<<<dim3(16, NB), 256, 0, stream>>>(patin, x, R0, inr_g, 0);
    for (int c = 0; c < NCH; c++) {
        kInnerOut<<<dim3(17, NB), 256, 0, stream>>>(R0, G_all, inr_g, q_g, wc_g, S_g, Beta, part, x, out, nblk, c);
        int du = (c + 1 < NCH) ? 1 : 0;
        const float* patread = (c == 0) ? patin : pat;
        if (nblk == 16)
            kStep<16><<<dim3(16, NB), 256, 0, stream>>>(pat, patread, x, q_g, wc_g, S_g, R0, inr_g, part, c, du);
        else
            kStep<8><<<dim3(8, NB), 256, 0, stream>>>(pat, patread, x, q_g, wc_g, S_g, R0, inr_g, part, c, du);
    }
    kOutRed<<<dim3(16, NB), 256, 0, stream>>>(part, x, Beta + (size_t)((NCH - 1) & 1) * NB * TC * TC, out, nblk, NCH - 1);
}